// Round 5
// baseline (419.710 us; speedup 1.0000x reference)
//
#include <hip/hip_runtime.h>
#include <hip/hip_bf16.h>
#include <math.h>

#define NN 256
#define NPAIR 32640            // 256*255/2
#define NSEG 32
#define MAT (NN*NN)            // 65536 floats

// float offsets inside d_ws  (total ~25.8 MB)
#define CS_U 0
#define CS_V (2*NPAIR)                 // 65280
#define MATS0 131072                   // 64 leaf matrices (U:0..31, V:32..63)
#define MATS1 (MATS0 + 64*MAT)         // up to 32 matrices; final U,V land here
#define WBT_OFF (MATS1 + 32*MAT)       // 65536 ushort (bf16 W^T[n][k])

// sweep boundaries: segment g = sweeps [BD[g], BD[g+1]), ~1020 rotations each
// (nearest-i to cumulative 255i - i(i-1)/2 = 1020g)
static __device__ const int BD[NSEG+1] =
    {0,4,8,12,17,21,25,30,34,39,44,49,54,59,64,69,75,81,87,93,99,
     106,113,120,128,136,145,155,165,177,192,210,255};

typedef __attribute__((ext_vector_type(8))) short short8;
typedef __attribute__((ext_vector_type(4))) float f32x4;

__device__ __forceinline__ short f2bf(float f) {
    __hip_bfloat16 h = __float2bfloat16(f);   // RNE
    return *reinterpret_cast<short*>(&h);
}

// ---------------- 1) cos/sin tables ----------------
__global__ __launch_bounds__(256) void k_sincos(const float* __restrict__ au,
                                                const float* __restrict__ av,
                                                float* __restrict__ ws) {
    int id = blockIdx.x * 256 + threadIdx.x;
    if (id < NPAIR) {
        float s, c;
        sincosf(au[id], &s, &c);
        ws[CS_U + 2*id]     = c;
        ws[CS_U + 2*id + 1] = s;
    } else if (id < 2*NPAIR) {
        int k = id - NPAIR;
        float s, c;
        sincosf(av[k], &s, &c);
        ws[CS_V + 2*k]     = c;
        ws[CS_V + 2*k + 1] = s;
    }
}

// ---------------- 2) segment partial products ----------------
// grid: 2 mats x 32 segs x 4 chunks = 256 blocks, 64 threads (1 wave).
// Segment product P (sweeps [i0,i1)) is [[I,0],[0,Q]] with split i0:
//   - cols < i0 are exactly e_c  -> all-identity chunks exit early
//   - rows < i0 are identity     -> LDS holds only rows >= i0
//   - sweep i with i+1 < c0: rotations j in [i+1,c0) cannot touch cols >= c0
//     (col c>i gains its first nonzero at j==c), so j starts at max(i+1,c0).
// 1-deep register prefetch: next group's cs (global) + rj (LDS) issued before
// current group's serial FMA chain -> latency hidden under compute.
__global__ __launch_bounds__(64) void k_build(const float* __restrict__ ws,
                                              float* __restrict__ mats) {
    int b = blockIdx.x;
    int matid = b >> 7;          // 0=U, 1=V
    int seg   = (b >> 2) & 31;
    int chunk = b & 3;
    int t = threadIdx.x;         // 0..63
    int c0 = chunk * 64;
    int i0 = BD[seg], i1 = BD[seg+1];
    float* outp = mats + (matid * NSEG + seg) * MAT;

    if (c0 + 64 <= i0) {         // whole chunk is identity columns
#pragma unroll 4
        for (int r = 0; r < NN; ++r)
            outp[r*NN + c0 + t] = (r == c0 + t) ? 1.0f : 0.0f;
        return;
    }

    __shared__ float M[NN * 64];     // rows [i0,256) x 64 cols used
    int MR = NN - i0;
    for (int rr = 0; rr < MR; ++rr)
        M[rr*64 + t] = (i0 + rr == c0 + t) ? 1.0f : 0.0f;

    const float* cs = ws + (matid ? CS_V : CS_U);

    for (int i = i0; i < i1; ++i) {
        int jstart = (i + 1 > c0) ? (i + 1) : c0;
        int k = 255*i - (i*(i-1))/2 + (jstart - i - 1);
        float ri = M[(i - i0)*64 + t];
        int j = jstart;
        int ng = (NN - jstart) >> 3;

        float2 cb[8]; float rj[8];
        if (ng > 0) {
#pragma unroll
            for (int u = 0; u < 8; ++u) cb[u] = *(const float2*)(cs + 2*(k+u));
#pragma unroll
            for (int u = 0; u < 8; ++u) rj[u] = M[(j - i0 + u)*64 + t];
        }
        for (int g = 0; g < ng; ++g) {
            float2 cn[8]; float rn[8];
            if (g + 1 < ng) {     // prefetch next group (rows disjoint: no alias)
#pragma unroll
                for (int u = 0; u < 8; ++u) cn[u] = *(const float2*)(cs + 2*(k+8+u));
#pragma unroll
                for (int u = 0; u < 8; ++u) rn[u] = M[(j + 8 - i0 + u)*64 + t];
            }
#pragma unroll
            for (int u = 0; u < 8; ++u) {
                float wv = cb[u].y*ri + cb[u].x*rj[u];
                ri       = cb[u].x*ri - cb[u].y*rj[u];
                M[(j - i0 + u)*64 + t] = wv;
            }
#pragma unroll
            for (int u = 0; u < 8; ++u) { cb[u] = cn[u]; rj[u] = rn[u]; }
            j += 8; k += 8;
        }
        int rem = NN - j;             // 0..7, wave-uniform
        if (rem > 0) {
            float2 cc[7]; float r7[7];
#pragma unroll
            for (int u = 0; u < 7; ++u)
                if (u < rem) { cc[u] = *(const float2*)(cs + 2*(k+u));
                               r7[u] = M[(j - i0 + u)*64 + t]; }
#pragma unroll
            for (int u = 0; u < 7; ++u)
                if (u < rem) {
                    float wv = cc[u].y*ri + cc[u].x*r7[u];
                    ri       = cc[u].x*ri - cc[u].y*r7[u];
                    M[(j - i0 + u)*64 + t] = wv;
                }
        }
        M[(i - i0)*64 + t] = ri;
    }

    for (int r = 0; r < i0; ++r)                 // identity rows
        outp[r*NN + c0 + t] = (r == c0 + t) ? 1.0f : 0.0f;
#pragma unroll 4
    for (int rr = 0; rr < MR; ++rr)              // computed rows
        outp[(i0 + rr)*NN + c0 + t] = M[rr*64 + t];
}

// ---------------- 3) tree fold: C = A @ B, structure-aware ----------------
// A = product of segs [q*span+span/2,(q+1)*span)  (split i0A = BD[...])
// B = product of segs [q*span, q*span+span/2)     (split i0B)
// C rows < i0B: identity.  rows in [i0B,i0A): copy of B (A row = e_r).
// rows >= i0A: dot over k >= i0A only (A exactly 0 left of split).
// m in low bits -> XCD-affine (same product's tiles share an L2).
__global__ __launch_bounds__(256) void k_fold(const float* __restrict__ in,
                                              float* __restrict__ out,
                                              int nOut, int lg, int span) {
    int b = blockIdx.x;
    int np2 = 2 * nOut;
    int m    = b & (np2 - 1);
    int tile = b >> lg;             // 0..127 = 32 rowtiles x 4 coltiles
    int side = (m >= nOut) ? 1 : 0;
    int q = m - side * nOut;
    const float* A = in + (side*np2 + 2*q + 1) * MAT;
    const float* B = in + (side*np2 + 2*q) * MAT;
    float* C = out + m * MAT;
    int i0B = BD[q * span];
    int i0A = BD[q * span + (span >> 1)];

    int r = (tile >> 2) * 8 + (threadIdx.x >> 5);
    int c = (tile & 3) * 64 + (threadIdx.x & 31) * 2;

    if (r < i0B) {
        float2 o = {(float)(r == c), (float)(r == c + 1)};
        *(float2*)(C + r * NN + c) = o;
        return;
    }
    if (r < i0A) {
        *(float2*)(C + r * NN + c) = *(const float2*)(B + r * NN + c);
        return;
    }

    int k0 = i0A & ~15;             // extra k's read A zeros -> exact
    float accx = 0.f, accy = 0.f;
    const float* Ar = A + r * NN;
    for (int kk0 = k0; kk0 < NN; kk0 += 16) {
        float4 a4[4];
#pragma unroll
        for (int u = 0; u < 4; ++u) a4[u] = *(const float4*)(Ar + kk0 + u*4);
        float2 b2[16];
#pragma unroll
        for (int kk = 0; kk < 16; ++kk) b2[kk] = *(const float2*)(B + (kk0+kk)*NN + c);
#pragma unroll
        for (int kk = 0; kk < 16; ++kk) {
            float av = ((const float*)a4)[kk];
            accx = fmaf(av, b2[kk].x, accx);
            accy = fmaf(av, b2[kk].y, accy);
        }
    }
    float2 o = {accx, accy};
    *(float2*)(C + r * NN + c) = o;
}

// ------- 4) Wbt[n][i] = bf16( sum_k U[i][k] S[k] V[n][k] ), 256 blocks -------
__global__ __launch_bounds__(256) void k_wmatT(const float* __restrict__ U,
                                               const float* __restrict__ V,
                                               const float* __restrict__ S,
                                               unsigned short* __restrict__ Wbt) {
    int b = blockIdx.x;
    int n0 = (b >> 4) * 16, i0 = (b & 15) * 16;
    int t = threadIdx.x, ti = t & 15, tn = t >> 4;
    __shared__ float Us[16][260];    // U*S rows (i-tile), +4 pad
    __shared__ float Vs[16][260];    // V rows (n-tile)
    {
        int rr = t >> 4, cc = (t & 15) * 16;
#pragma unroll
        for (int q = 0; q < 4; ++q) {
            float4 u = *(const float4*)(U + (i0+rr)*NN + cc + q*4);
            float4 s = *(const float4*)(S + cc + q*4);
            u.x *= s.x; u.y *= s.y; u.z *= s.z; u.w *= s.w;
            *(float4*)&Us[rr][cc+q*4] = u;
            *(float4*)&Vs[rr][cc+q*4] = *(const float4*)(V + (n0+rr)*NN + cc + q*4);
        }
    }
    __syncthreads();
    float acc = 0.f;
#pragma unroll 8
    for (int k4 = 0; k4 < 64; ++k4) {
        float4 uu = *(const float4*)&Us[ti][k4*4];
        float4 vv = *(const float4*)&Vs[tn][k4*4];
        acc += uu.x*vv.x + uu.y*vv.y + uu.z*vv.z + uu.w*vv.w;
    }
    Wbt[(n0+tn)*NN + (i0+ti)] = (unsigned short)f2bf(acc);
}

// ---------------- 5) out = x @ W + bias : bf16 MFMA, x via LDS ---------------
// 1024 blocks x 512 thr (8 waves) = 4 blocks/CU = 32 waves/CU (max occupancy).
// Wave w owns output cols [32w,32w+32), its W slice in 64 VGPRs. x staged once
// per block (f32->bf16 during staging) into LDS; double-buffered with next
// tile's global loads issued before the barrier (T14).
__global__ __launch_bounds__(512, 4) void k_mm(const float* __restrict__ x,
                                               const unsigned short* __restrict__ Wbt,
                                               const float* __restrict__ bias,
                                               float* __restrict__ out) {
    int t = threadIdx.x;
    int w = t >> 6, l = t & 63, l15 = l & 15, lg = l >> 4;
    int n0 = w * 32;

    __shared__ unsigned short Xs[2][16 * 264];   // 16 rows x 256 bf16, pad 8

    // B-fragments: lane holds col n0+nt*16+l15, k = ks*32 + lg*8 + e
    short8 bfrag[2][8];
#pragma unroll
    for (int nt = 0; nt < 2; ++nt) {
        const unsigned short* wrow = Wbt + (n0 + nt*16 + l15) * NN + lg * 8;
#pragma unroll
        for (int ks = 0; ks < 8; ++ks)
            bfrag[nt][ks] = *(const short8*)(wrow + ks * 32);
    }
    float b0 = bias[n0 + l15];
    float b1 = bias[n0 + 16 + l15];

    int row  = t >> 5;          // 0..15  (staging row)
    int col8 = (t & 31) * 8;    // 0..248 (staging col)

    int tile = blockIdx.x;
    const float* src = x + (long)tile * 4096 + row * NN + col8;
    float4 f0 = *(const float4*)(src);
    float4 f1 = *(const float4*)(src + 4);

    for (int it = 0; it < 8; ++it, tile += 1024) {
        int cur = it & 1;
        short8 h;
        h[0]=f2bf(f0.x); h[1]=f2bf(f0.y); h[2]=f2bf(f0.z); h[3]=f2bf(f0.w);
        h[4]=f2bf(f1.x); h[5]=f2bf(f1.y); h[6]=f2bf(f1.z); h[7]=f2bf(f1.w);
        *(short8*)&Xs[cur][row * 264 + col8] = h;
        if (it < 7) {           // issue next tile's loads across barrier+compute
            const float* s2 = x + (long)(tile + 1024) * 4096 + row * NN + col8;
            f0 = *(const float4*)(s2);
            f1 = *(const float4*)(s2 + 4);
        }
        __syncthreads();

        f32x4 acc0 = {0.f,0.f,0.f,0.f}, acc1 = {0.f,0.f,0.f,0.f};
        const unsigned short* xs = &Xs[cur][l15 * 264 + lg * 8];
#pragma unroll
        for (int ks = 0; ks < 8; ++ks) {
            short8 af = *(const short8*)(xs + ks * 32);
            acc0 = __builtin_amdgcn_mfma_f32_16x16x32_bf16(af, bfrag[0][ks], acc0, 0, 0, 0);
            acc1 = __builtin_amdgcn_mfma_f32_16x16x32_bf16(af, bfrag[1][ks], acc1, 0, 0, 0);
        }
        // D: col = lane&15, row = (lane>>4)*4 + reg
        float* op = out + ((long)tile * 16 + lg * 4) * NN + n0 + l15;
#pragma unroll
        for (int r = 0; r < 4; ++r) {
            op[r * NN]      = acc0[r] + b0;
            op[r * NN + 16] = acc1[r] + b1;
        }
    }
}

extern "C" void kernel_launch(void* const* d_in, const int* in_sizes, int n_in,
                              void* d_out, int out_size, void* d_ws, size_t ws_size,
                              hipStream_t stream) {
    const float* x    = (const float*)d_in[0];
    const float* Uw   = (const float*)d_in[1];
    const float* Vw   = (const float*)d_in[2];
    const float* Sw   = (const float*)d_in[3];
    const float* bias = (const float*)d_in[4];
    float* out = (float*)d_out;
    float* ws  = (float*)d_ws;

    k_sincos<<<255, 256, 0, stream>>>(Uw, Vw, ws);
    // 32 sweep-aligned segment products per matrix (triangular-structure-aware)
    k_build<<<256, 64, 0, stream>>>(ws, ws + MATS0);
    // fold 32 -> 16 -> 8 -> 4 -> 2 -> 1 per side; final U,V land in MATS1
    k_fold<<<32*128, 256, 0, stream>>>(ws + MATS0, ws + MATS1, 16, 5, 2);
    k_fold<<<16*128, 256, 0, stream>>>(ws + MATS1, ws + MATS0,  8, 4, 4);
    k_fold<<< 8*128, 256, 0, stream>>>(ws + MATS0, ws + MATS1,  4, 3, 8);
    k_fold<<< 4*128, 256, 0, stream>>>(ws + MATS1, ws + MATS0,  2, 2, 16);
    k_fold<<< 2*128, 256, 0, stream>>>(ws + MATS0, ws + MATS1,  1, 1, 32);
    // Wbt = bf16( (U S V^T)^T ), [n][k] layout
    k_wmatT<<<256, 256, 0, stream>>>(ws + MATS1, ws + MATS1 + MAT, Sw,
                                     (unsigned short*)(ws + WBT_OFF));
    // out = x @ W + bias (bf16 MFMA, LDS-staged x)
    k_mm<<<1024, 512, 0, stream>>>(x, (unsigned short*)(ws + WBT_OFF), bias, out);
}

// Round 7
// 194.623 us; speedup vs baseline: 2.1565x; 2.1565x over previous
//
#include <hip/hip_runtime.h>
#include <hip/hip_bf16.h>
#include <math.h>

#define NN 256
#define NPAIR 32640            // 256*255/2
#define NSEG 32
#define MAT (NN*NN)            // 65536 floats

// float offsets inside d_ws  (total ~25.8 MB)
#define CS_U 0
#define CS_V (2*NPAIR)                 // 65280
#define MATS0 131072                   // 64 leaf matrices (U:0..31, V:32..63)
#define MATS1 (MATS0 + 64*MAT)         // 32 matrices; final U,V land here
#define WBT_OFF (MATS1 + 32*MAT)       // 65536 ushort (bf16 W^T[n][k])

// sweep boundaries: segment g = sweeps [BD[g], BD[g+1]).
// Chosen greedily so nrot(g) = k(BD[g+1])-k(BD[g]) <= 1120 for ALL g
// (k(i) = 255i - i(i-1)/2; max realized nrot = 1113; r6 bug: old table
// reached 1205 and overflowed csl[1040] -> zeroed rotations -> W ~ 0).
static __device__ const int BD[NSEG+1] =
    {0,4,8,12,16,20,24,28,32,37,42,47,52,57,62,67,73,79,85,91,97,
     104,111,118,126,134,143,153,164,177,192,213,255};
#define CSL_CAP 1120

typedef __attribute__((ext_vector_type(8))) short short8;
typedef __attribute__((ext_vector_type(4))) float f32x4;

__device__ __forceinline__ short f2bf(float f) {
    __hip_bfloat16 h = __float2bfloat16(f);   // RNE
    return *reinterpret_cast<short*>(&h);
}

// ---------------- 1) cos/sin tables ----------------
__global__ __launch_bounds__(256) void k_sincos(const float* __restrict__ au,
                                                const float* __restrict__ av,
                                                float* __restrict__ ws) {
    int id = blockIdx.x * 256 + threadIdx.x;
    if (id < NPAIR) {
        float s, c;
        sincosf(au[id], &s, &c);
        ws[CS_U + 2*id]     = c;
        ws[CS_U + 2*id + 1] = s;
    } else if (id < 2*NPAIR) {
        int k = id - NPAIR;
        float s, c;
        sincosf(av[k], &s, &c);
        ws[CS_V + 2*k]     = c;
        ws[CS_V + 2*k + 1] = s;
    }
}

// ---------------- 2) segment partial products ----------------
// 2 mats x 32 segs x 4 chunks = 256 blocks, 64 threads (1 wave).
// Whole segment's (cos,sin) table staged into LDS first (<=1120 pairs,
// coalesced); rotation loop touches ONLY LDS, 1-deep prefetch hides latency.
// LDS total 74.5 KB (gfx950 allows up to 160 KB/workgroup).
__global__ __launch_bounds__(64) void k_build(const float* __restrict__ ws,
                                              float* __restrict__ mats) {
    int b = blockIdx.x;
    int matid = b >> 7;          // 0=U, 1=V
    int seg   = (b >> 2) & 31;
    int chunk = b & 3;
    int t = threadIdx.x;         // 0..63
    int c0 = chunk * 64;
    int i0 = BD[seg], i1 = BD[seg+1];
    float* outp = mats + (matid * NSEG + seg) * MAT;

    if (c0 + 64 <= i0) {         // whole chunk is identity columns
        for (int id = t; id < 4096; id += 64) {
            int row = id >> 4, c4 = (id & 15) * 4;
            float4 v = {0.f,0.f,0.f,0.f};
            int d = row - (c0 + c4);
            if (d >= 0 && d < 4) ((float*)&v)[d] = 1.0f;
            *(float4*)(outp + row*NN + c0 + c4) = v;
        }
        return;
    }

    __shared__ float M[NN * 64];       // rows [i0,256) x 64 cols
    __shared__ float2 csl[CSL_CAP];    // segment cos/sin table (max 1113)

    int kbase = 255*i0 - (i0*(i0-1))/2;
    int kend  = 255*i1 - (i1*(i1-1))/2;
    int nrot  = kend - kbase;          // <= CSL_CAP by BD construction
    const float* cs = ws + (matid ? CS_V : CS_U) + 2*kbase;
    for (int idx = t; idx < nrot; idx += 64)
        csl[idx] = *(const float2*)(cs + 2*idx);

    int MR = NN - i0;
    for (int rr = 0; rr < MR; ++rr)
        M[rr*64 + t] = (i0 + rr == c0 + t) ? 1.0f : 0.0f;
    __syncthreads();

    for (int i = i0; i < i1; ++i) {
        int jstart = (i + 1 > c0) ? (i + 1) : c0;
        int kl = 255*i - (i*(i-1))/2 + (jstart - i - 1) - kbase;
        float ri = M[(i - i0)*64 + t];
        int j = jstart;
        int ng = (NN - jstart) >> 3;

        float2 cb[8]; float rj[8];
        if (ng > 0) {
#pragma unroll
            for (int u = 0; u < 8; ++u) cb[u] = csl[kl + u];
#pragma unroll
            for (int u = 0; u < 8; ++u) rj[u] = M[(j - i0 + u)*64 + t];
        }
        for (int g = 0; g < ng; ++g) {
            float2 cn[8]; float rn[8];
            if (g + 1 < ng) {     // prefetch next group (rows disjoint)
#pragma unroll
                for (int u = 0; u < 8; ++u) cn[u] = csl[kl + 8 + u];
#pragma unroll
                for (int u = 0; u < 8; ++u) rn[u] = M[(j + 8 - i0 + u)*64 + t];
            }
#pragma unroll
            for (int u = 0; u < 8; ++u) {
                float wv = cb[u].y*ri + cb[u].x*rj[u];
                ri       = cb[u].x*ri - cb[u].y*rj[u];
                M[(j - i0 + u)*64 + t] = wv;
            }
#pragma unroll
            for (int u = 0; u < 8; ++u) { cb[u] = cn[u]; rj[u] = rn[u]; }
            j += 8; kl += 8;
        }
        int rem = NN - j;             // 0..7, wave-uniform
        if (rem > 0) {
            float2 cc[7]; float r7[7];
#pragma unroll
            for (int u = 0; u < 7; ++u)
                if (u < rem) { cc[u] = csl[kl + u];
                               r7[u] = M[(j - i0 + u)*64 + t]; }
#pragma unroll
            for (int u = 0; u < 7; ++u)
                if (u < rem) {
                    float wv = cc[u].y*ri + cc[u].x*r7[u];
                    ri       = cc[u].x*ri - cc[u].y*r7[u];
                    M[(j - i0 + u)*64 + t] = wv;
                }
        }
        M[(i - i0)*64 + t] = ri;
    }
    __syncthreads();

    // writeout: float4 per lane; rows < i0 are identity
    for (int id = t; id < 4096; id += 64) {
        int row = id >> 4, c4 = (id & 15) * 4;
        float4 v;
        if (row < i0) {
            v = make_float4(0.f,0.f,0.f,0.f);
            int d = row - (c0 + c4);
            if (d >= 0 && d < 4) ((float*)&v)[d] = 1.0f;
        } else {
            v = *(const float4*)&M[(row - i0)*64 + c4];
        }
        *(float4*)(outp + row*NN + c0 + c4) = v;
    }
}

// ---------------- 3) tree fold: C = A @ B, LDS-staged dbuf GEMM -------------
// 64x64 tile, KT=32, Ast stored transposed [k][row] for b128 compute reads.
// Single-barrier double buffer (k_mm pattern). Structure: tiles fully below
// i0A are an exact copy of B; GEMM k-range starts at min(r0,i0A)&~31 (exact:
// A has identity rows below i0A and exact zeros left of its dense block).
// m in low bits -> XCD-affine for np2>=8.
__global__ __launch_bounds__(256) void k_fold(const float* __restrict__ in,
                                              float* __restrict__ out,
                                              int nOut, int lg, int span) {
    int b = blockIdx.x;
    int np2 = 2 * nOut;
    int m    = b & (np2 - 1);
    int tile = b >> lg;             // 0..15 = 4 rowtiles x 4 coltiles
    int side = (m >= nOut) ? 1 : 0;
    int q = m - side * nOut;
    const float* A = in + (side*np2 + 2*q + 1) * MAT;
    const float* B = in + (side*np2 + 2*q) * MAT;
    float* C = out + m * MAT;
    int i0A = BD[q * span + (span >> 1)];
    int r0 = (tile >> 2) * 64, c0 = (tile & 3) * 64;
    int t = threadIdx.x;

    if (r0 + 64 <= i0A) {           // copy tile (exact)
#pragma unroll
        for (int u = 0; u < 4; ++u) {
            int id = u*256 + t;
            int rr = id >> 4, cc = (id & 15) * 4;
            *(float4*)(C + (r0+rr)*NN + c0 + cc) =
                *(const float4*)(B + (r0+rr)*NN + c0 + cc);
        }
        return;
    }

    int kstart = ((r0 < i0A) ? r0 : i0A) & ~31;
    int nt = (NN - kstart) >> 5;

    __shared__ float Ast[2][32][68];   // [buf][k][row]
    __shared__ float Bs [2][32][68];   // [buf][k][col]
    int tx = t & 15, ty = t >> 4;
    int arow = t >> 3, ak4 = t & 7;    // A f4: rows arow,arow+32; k-quad ak4
    int bkr = t >> 4, bc4 = t & 15;    // B f4: k=bkr,bkr+16; col-quad bc4

    float acc[4][4] = {};
    f32x4 pa0, pa1, pb0, pb1;
    {
        int kt = kstart;
        pa0 = *(const f32x4*)(A + (r0 + arow     )*NN + kt + ak4*4);
        pa1 = *(const f32x4*)(A + (r0 + arow + 32)*NN + kt + ak4*4);
        pb0 = *(const f32x4*)(B + (kt + bkr      )*NN + c0 + bc4*4);
        pb1 = *(const f32x4*)(B + (kt + bkr + 16 )*NN + c0 + bc4*4);
    }
    for (int it = 0; it < nt; ++it) {
        int cur = it & 1;
#pragma unroll
        for (int jj = 0; jj < 4; ++jj) {
            Ast[cur][ak4*4 + jj][arow]      = pa0[jj];
            Ast[cur][ak4*4 + jj][arow + 32] = pa1[jj];
        }
        *(f32x4*)&Bs[cur][bkr     ][bc4*4] = pb0;
        *(f32x4*)&Bs[cur][bkr + 16][bc4*4] = pb1;
        if (it + 1 < nt) {           // issue next k-tile loads across barrier
            int k2 = kstart + (it+1)*32;
            pa0 = *(const f32x4*)(A + (r0 + arow     )*NN + k2 + ak4*4);
            pa1 = *(const f32x4*)(A + (r0 + arow + 32)*NN + k2 + ak4*4);
            pb0 = *(const f32x4*)(B + (k2 + bkr      )*NN + c0 + bc4*4);
            pb1 = *(const f32x4*)(B + (k2 + bkr + 16 )*NN + c0 + bc4*4);
        }
        __syncthreads();
#pragma unroll 8
        for (int kk = 0; kk < 32; ++kk) {
            f32x4 a4 = *(const f32x4*)&Ast[cur][kk][ty*4];
            f32x4 b4 = *(const f32x4*)&Bs [cur][kk][tx*4];
#pragma unroll
            for (int rr = 0; rr < 4; ++rr)
#pragma unroll
                for (int cc = 0; cc < 4; ++cc)
                    acc[rr][cc] = fmaf(a4[rr], b4[cc], acc[rr][cc]);
        }
    }
#pragma unroll
    for (int rr = 0; rr < 4; ++rr) {
        float4 o = {acc[rr][0], acc[rr][1], acc[rr][2], acc[rr][3]};
        *(float4*)(C + (r0 + ty*4 + rr)*NN + c0 + tx*4) = o;
    }
}

// ------- 4) Wbt[n][i] = bf16( sum_k U[i][k] S[k] V[n][k] ), 256 blocks -------
__global__ __launch_bounds__(256) void k_wmatT(const float* __restrict__ U,
                                               const float* __restrict__ V,
                                               const float* __restrict__ S,
                                               unsigned short* __restrict__ Wbt) {
    int b = blockIdx.x;
    int n0 = (b >> 4) * 16, i0 = (b & 15) * 16;
    int t = threadIdx.x, ti = t & 15, tn = t >> 4;
    __shared__ float Us[16][260];
    __shared__ float Vs[16][260];
    {
        int rr = t >> 4, cc = (t & 15) * 16;
#pragma unroll
        for (int q = 0; q < 4; ++q) {
            float4 u = *(const float4*)(U + (i0+rr)*NN + cc + q*4);
            float4 s = *(const float4*)(S + cc + q*4);
            u.x *= s.x; u.y *= s.y; u.z *= s.z; u.w *= s.w;
            *(float4*)&Us[rr][cc+q*4] = u;
            *(float4*)&Vs[rr][cc+q*4] = *(const float4*)(V + (n0+rr)*NN + cc + q*4);
        }
    }
    __syncthreads();
    float acc = 0.f;
#pragma unroll 8
    for (int k4 = 0; k4 < 64; ++k4) {
        float4 uu = *(const float4*)&Us[ti][k4*4];
        float4 vv = *(const float4*)&Vs[tn][k4*4];
        acc += uu.x*vv.x + uu.y*vv.y + uu.z*vv.z + uu.w*vv.w;
    }
    Wbt[(n0+tn)*NN + (i0+ti)] = (unsigned short)f2bf(acc);
}

// ---------------- 5) out = x @ W + bias : bf16 MFMA, x via LDS ---------------
__global__ __launch_bounds__(512, 4) void k_mm(const float* __restrict__ x,
                                               const unsigned short* __restrict__ Wbt,
                                               const float* __restrict__ bias,
                                               float* __restrict__ out) {
    int t = threadIdx.x;
    int w = t >> 6, l = t & 63, l15 = l & 15, lg = l >> 4;
    int n0 = w * 32;

    __shared__ unsigned short Xs[2][16 * 264];

    short8 bfrag[2][8];
#pragma unroll
    for (int nt = 0; nt < 2; ++nt) {
        const unsigned short* wrow = Wbt + (n0 + nt*16 + l15) * NN + lg * 8;
#pragma unroll
        for (int ks = 0; ks < 8; ++ks)
            bfrag[nt][ks] = *(const short8*)(wrow + ks * 32);
    }
    float b0 = bias[n0 + l15];
    float b1 = bias[n0 + 16 + l15];

    int row  = t >> 5;
    int col8 = (t & 31) * 8;

    int tile = blockIdx.x;
    const float* src = x + (long)tile * 4096 + row * NN + col8;
    float4 f0 = *(const float4*)(src);
    float4 f1 = *(const float4*)(src + 4);

    for (int it = 0; it < 8; ++it, tile += 1024) {
        int cur = it & 1;
        short8 h;
        h[0]=f2bf(f0.x); h[1]=f2bf(f0.y); h[2]=f2bf(f0.z); h[3]=f2bf(f0.w);
        h[4]=f2bf(f1.x); h[5]=f2bf(f1.y); h[6]=f2bf(f1.z); h[7]=f2bf(f1.w);
        *(short8*)&Xs[cur][row * 264 + col8] = h;
        if (it < 7) {
            const float* s2 = x + (long)(tile + 1024) * 4096 + row * NN + col8;
            f0 = *(const float4*)(s2);
            f1 = *(const float4*)(s2 + 4);
        }
        __syncthreads();

        f32x4 acc0 = {0.f,0.f,0.f,0.f}, acc1 = {0.f,0.f,0.f,0.f};
        const unsigned short* xs = &Xs[cur][l15 * 264 + lg * 8];
#pragma unroll
        for (int ks = 0; ks < 8; ++ks) {
            short8 af = *(const short8*)(xs + ks * 32);
            acc0 = __builtin_amdgcn_mfma_f32_16x16x32_bf16(af, bfrag[0][ks], acc0, 0, 0, 0);
            acc1 = __builtin_amdgcn_mfma_f32_16x16x32_bf16(af, bfrag[1][ks], acc1, 0, 0, 0);
        }
        float* op = out + ((long)tile * 16 + lg * 4) * NN + n0 + l15;
#pragma unroll
        for (int r = 0; r < 4; ++r) {
            op[r * NN]      = acc0[r] + b0;
            op[r * NN + 16] = acc1[r] + b1;
        }
    }
}

extern "C" void kernel_launch(void* const* d_in, const int* in_sizes, int n_in,
                              void* d_out, int out_size, void* d_ws, size_t ws_size,
                              hipStream_t stream) {
    const float* x    = (const float*)d_in[0];
    const float* Uw   = (const float*)d_in[1];
    const float* Vw   = (const float*)d_in[2];
    const float* Sw   = (const float*)d_in[3];
    const float* bias = (const float*)d_in[4];
    float* out = (float*)d_out;
    float* ws  = (float*)d_ws;

    k_sincos<<<255, 256, 0, stream>>>(Uw, Vw, ws);
    // 32 sweep-aligned segment products per matrix (cs table in LDS)
    k_build<<<256, 64, 0, stream>>>(ws, ws + MATS0);
    // fold 32 -> 16 -> 8 -> 4 -> 2 -> 1 per side; final U,V land in MATS1
    k_fold<<<16*32, 256, 0, stream>>>(ws + MATS0, ws + MATS1, 16, 5, 2);
    k_fold<<<16*16, 256, 0, stream>>>(ws + MATS1, ws + MATS0,  8, 4, 4);
    k_fold<<<16* 8, 256, 0, stream>>>(ws + MATS0, ws + MATS1,  4, 3, 8);
    k_fold<<<16* 4, 256, 0, stream>>>(ws + MATS1, ws + MATS0,  2, 2, 16);
    k_fold<<<16* 2, 256, 0, stream>>>(ws + MATS0, ws + MATS1,  1, 1, 32);
    // Wbt = bf16( (U S V^T)^T ), [n][k] layout
    k_wmatT<<<256, 256, 0, stream>>>(ws + MATS1, ws + MATS1 + MAT, Sw,
                                     (unsigned short*)(ws + WBT_OFF));
    // out = x @ W + bias (bf16 MFMA, LDS-staged x)
    k_mm<<<1024, 512, 0, stream>>>(x, (unsigned short*)(ws + WBT_OFF), bias, out);
}